// Round 2
// baseline (44.746 us; speedup 1.0000x reference)
//
#include <hip/hip_runtime.h>
#include <hip/hip_bf16.h>

// Problem constants (from reference setup_inputs)
#define NB 8192   // batch
#define NH 8      // heads
#define ND 512    // D
#define NO 256    // DO
#define ROWS 16   // batch rows per block

typedef __attribute__((ext_vector_type(8))) short short8;
typedef __attribute__((ext_vector_type(4))) float f32x4;

// W converted to bf16 once per launch (256 KB, L2-resident during GEMM phase)
__device__ __align__(16) ushort g_wb[NO * ND];

__device__ __forceinline__ ushort f2bf(float f) {
    union { float f; unsigned u; } v; v.f = f;
    unsigned u = v.u;
    unsigned r = u + 0x7FFFu + ((u >> 16) & 1u);   // round-to-nearest-even
    return (ushort)(r >> 16);
}

__global__ __launch_bounds__(256) void wcvt_kernel(const float* __restrict__ W) {
    int i = (blockIdx.x * 256 + threadIdx.x) * 4;
    float4 w = *(const float4*)(W + i);
    ushort4 o;
    o.x = f2bf(w.x); o.y = f2bf(w.y); o.z = f2bf(w.z); o.w = f2bf(w.w);
    *(ushort4*)(g_wb + i) = o;
}

__device__ __forceinline__ float swishf(float h) {
    // h * sigmoid(h); overflow-safe: h<<0 -> exp(-h)=inf -> rcp=0 -> -0
    return h * __builtin_amdgcn_rcpf(1.0f + __expf(-h));
}

__global__ __launch_bounds__(256) void fused_kernel(
    const float* __restrict__ x, const float* __restrict__ rw,
    const float* __restrict__ gamma, const float* __restrict__ beta,
    const float* __restrict__ mean, const float* __restrict__ var,
    const float* __restrict__ bias, float* __restrict__ out)
{
    // y-tile: ROWS x ND bf16, row pitch 1024 B, XOR-swizzled within row
    __shared__ __align__(16) ushort yl[ROWS * ND];
    __shared__ float sumw[ROWS];

    const int tid = threadIdx.x;
    const int b0  = blockIdx.x * ROWS;

    // ---------------- phase 1: BN + swish + head-weighted reduce ----------------
    // 128 threads cover D=512 as float4 chunks; 2 rows in flight (tid>>7)
    const int d4 = tid & 127;
    const int rh = tid >> 7;
    const int d  = d4 * 4;

    float4 g4 = *(const float4*)(gamma + d);
    float4 v4 = *(const float4*)(var   + d);
    float4 be = *(const float4*)(beta  + d);
    float4 me = *(const float4*)(mean  + d);
    const float ix = g4.x * rsqrtf(v4.x + 1e-5f);
    const float iy = g4.y * rsqrtf(v4.y + 1e-5f);
    const float iz = g4.z * rsqrtf(v4.z + 1e-5f);
    const float iw = g4.w * rsqrtf(v4.w + 1e-5f);
    const float ox = be.x - me.x * ix;
    const float oy = be.y - me.y * iy;
    const float oz = be.z - me.z * iz;
    const float ow = be.w - me.w * iw;

    for (int rr = rh; rr < ROWS; rr += 2) {
        const int b = b0 + rr;
        const float* xr  = x + (size_t)b * (NH * ND) + d;
        const float* rwr = rw + b * NH;
        float ax = 0.f, ay = 0.f, az = 0.f, aw = 0.f, sumr = 0.f;
        #pragma unroll
        for (int h = 0; h < NH; ++h) {
            float4 xa = *(const float4*)(xr + h * ND);
            float wh = rwr[h];
            sumr += wh;
            ax += wh * swishf(xa.x * ix + ox);
            ay += wh * swishf(xa.y * iy + oy);
            az += wh * swishf(xa.z * iz + oz);
            aw += wh * swishf(xa.w * iw + ow);
        }
        const int addr = rr * 1024 + ((d * 2) ^ ((rr & 7) << 4));
        ushort4 o;
        o.x = f2bf(ax); o.y = f2bf(ay); o.z = f2bf(az); o.w = f2bf(aw);
        *(ushort4*)((char*)yl + addr) = o;
        if (d4 == 0) sumw[rr] = sumr;
    }
    __syncthreads();

    // ---------------- phase 2: [16 x 512] @ W^T via bf16 MFMA ----------------
    // 4 waves, each owns 64 output cols (4 n-fragments of 16)
    const int lane = tid & 63;
    const int wv   = tid >> 6;
    const int n0   = wv * 64;
    const int lr   = lane & 15;          // A-row / B-col-within-frag
    const int lk   = (lane >> 4) * 8;    // k offset within 32

    f32x4 acc0 = {0.f,0.f,0.f,0.f};
    f32x4 acc1 = {0.f,0.f,0.f,0.f};
    f32x4 acc2 = {0.f,0.f,0.f,0.f};
    f32x4 acc3 = {0.f,0.f,0.f,0.f};

    const char* ylb = (const char*)yl + lr * 1024;
    const int swz = (lr & 7) << 4;

    #pragma unroll 4
    for (int ks = 0; ks < 16; ++ks) {
        const int k0 = ks * 32;
        const int kb = (k0 + lk) * 2;
        short8 a = *(const short8*)(ylb + (kb ^ swz));
        const ushort* wp = g_wb + (size_t)(n0 + lr) * ND + k0 + lk;
        short8 bf0 = *(const short8*)(wp);
        short8 bf1 = *(const short8*)(wp + 16 * ND);
        short8 bf2 = *(const short8*)(wp + 32 * ND);
        short8 bf3 = *(const short8*)(wp + 48 * ND);
        acc0 = __builtin_amdgcn_mfma_f32_16x16x32_bf16(a, bf0, acc0, 0, 0, 0);
        acc1 = __builtin_amdgcn_mfma_f32_16x16x32_bf16(a, bf1, acc1, 0, 0, 0);
        acc2 = __builtin_amdgcn_mfma_f32_16x16x32_bf16(a, bf2, acc2, 0, 0, 0);
        acc3 = __builtin_amdgcn_mfma_f32_16x16x32_bf16(a, bf3, acc3, 0, 0, 0);
    }

    // epilogue: D layout col = lane&15, row = (lane>>4)*4 + reg
    const int rbase = (lane >> 4) * 4;
    f32x4 accs[4] = {acc0, acc1, acc2, acc3};
    #pragma unroll
    for (int nf = 0; nf < 4; ++nf) {
        const int col = n0 + nf * 16 + lr;
        const float bn = bias[col];
        #pragma unroll
        for (int q = 0; q < 4; ++q) {
            const int r = rbase + q;
            out[(size_t)(b0 + r) * NO + col] = accs[nf][q] + bn * sumw[r];
        }
    }
}

extern "C" void kernel_launch(void* const* d_in, const int* in_sizes, int n_in,
                              void* d_out, int out_size, void* d_ws, size_t ws_size,
                              hipStream_t stream) {
    const float* x     = (const float*)d_in[0];
    const float* rw    = (const float*)d_in[1];
    const float* gamma = (const float*)d_in[2];
    const float* beta  = (const float*)d_in[3];
    const float* mean  = (const float*)d_in[4];
    const float* var   = (const float*)d_in[5];
    const float* W     = (const float*)d_in[6];
    const float* bias  = (const float*)d_in[7];
    float* out = (float*)d_out;

    hipLaunchKernelGGL(wcvt_kernel, dim3((NO * ND) / 1024), dim3(256), 0, stream, W);
    hipLaunchKernelGGL(fused_kernel, dim3(NB / ROWS), dim3(256), 0, stream,
                       x, rw, gamma, beta, mean, var, bias, out);
}

// Round 3
// 44.537 us; speedup vs baseline: 1.0047x; 1.0047x over previous
//
#include <hip/hip_runtime.h>
#include <hip/hip_bf16.h>

// Problem constants (from reference setup_inputs)
#define NB 8192   // batch
#define NH 8      // heads
#define ND 512    // D
#define NO 256    // DO
#define ROWS 16   // batch rows per block
#define TPB 512   // threads per block (8 waves)

typedef __attribute__((ext_vector_type(8))) short short8;
typedef __attribute__((ext_vector_type(4))) float f32x4;

// W converted to bf16 once per launch (256 KB, L2-resident during GEMM phase)
__device__ __align__(16) ushort g_wb[NO * ND];

__device__ __forceinline__ ushort f2bf(float f) {
    union { float f; unsigned u; } v; v.f = f;
    unsigned u = v.u;
    unsigned r = u + 0x7FFFu + ((u >> 16) & 1u);   // round-to-nearest-even
    return (ushort)(r >> 16);
}

__global__ __launch_bounds__(256) void wcvt_kernel(const float* __restrict__ W) {
    int i = (blockIdx.x * 256 + threadIdx.x) * 4;
    float4 w = *(const float4*)(W + i);
    ushort4 o;
    o.x = f2bf(w.x); o.y = f2bf(w.y); o.z = f2bf(w.z); o.w = f2bf(w.w);
    *(ushort4*)(g_wb + i) = o;
}

__device__ __forceinline__ float swishf(float h) {
    // h * sigmoid(h); overflow-safe: h<<0 -> exp(-h)=inf -> rcp=0 -> -0
    return h * __builtin_amdgcn_rcpf(1.0f + __expf(-h));
}

__global__ __launch_bounds__(TPB, 4) void fused_kernel(
    const float* __restrict__ x, const float* __restrict__ rw,
    const float* __restrict__ gamma, const float* __restrict__ beta,
    const float* __restrict__ mean, const float* __restrict__ var,
    const float* __restrict__ bias, float* __restrict__ out)
{
    // y-tile: ROWS x ND bf16, row pitch 1024 B, XOR-swizzled within row
    __shared__ __align__(16) ushort yl[ROWS * ND];
    __shared__ float sumw[ROWS];

    const int tid = threadIdx.x;
    const int b0  = blockIdx.x * ROWS;

    // ---------------- phase 1: BN + swish + head-weighted reduce ----------------
    // 128 threads cover D=512 as float4 chunks; 4 rows in flight (tid>>7),
    // software-pipelined over 4 iterations so loads overlap the swish VALU burst.
    const int d4 = tid & 127;
    const int rh = tid >> 7;          // 0..3
    const int d  = d4 * 4;

    float4 g4 = *(const float4*)(gamma + d);
    float4 v4 = *(const float4*)(var   + d);
    float4 be = *(const float4*)(beta  + d);
    float4 me = *(const float4*)(mean  + d);
    const float ix = g4.x * rsqrtf(v4.x + 1e-5f);
    const float iy = g4.y * rsqrtf(v4.y + 1e-5f);
    const float iz = g4.z * rsqrtf(v4.z + 1e-5f);
    const float iw = g4.w * rsqrtf(v4.w + 1e-5f);
    const float ox = be.x - me.x * ix;
    const float oy = be.y - me.y * iy;
    const float oz = be.z - me.z * iz;
    const float ow = be.w - me.w * iw;

    const float* xr = x + (size_t)(b0 + rh) * (NH * ND) + d;
    float4 cur[NH];
    #pragma unroll
    for (int h = 0; h < NH; ++h) cur[h] = *(const float4*)(xr + h * ND);

    #pragma unroll
    for (int it = 0; it < 4; ++it) {
        const int rr = rh + it * 4;
        float4 nxt[NH];
        if (it < 3) {
            const float* xn = xr + (size_t)4 * NH * ND;
            #pragma unroll
            for (int h = 0; h < NH; ++h) nxt[h] = *(const float4*)(xn + h * ND);
        }
        const float* rwr = rw + (b0 + rr) * NH;
        float4 w0 = *(const float4*)(rwr);
        float4 w1 = *(const float4*)(rwr + 4);
        const float whv[NH] = {w0.x, w0.y, w0.z, w0.w, w1.x, w1.y, w1.z, w1.w};

        float ax = 0.f, ay = 0.f, az = 0.f, aw = 0.f;
        #pragma unroll
        for (int h = 0; h < NH; ++h) {
            const float wh = whv[h];
            ax += wh * swishf(cur[h].x * ix + ox);
            ay += wh * swishf(cur[h].y * iy + oy);
            az += wh * swishf(cur[h].z * iz + oz);
            aw += wh * swishf(cur[h].w * iw + ow);
        }
        const int addr = rr * 1024 + ((d * 2) ^ ((rr & 7) << 4));
        ushort4 o;
        o.x = f2bf(ax); o.y = f2bf(ay); o.z = f2bf(az); o.w = f2bf(aw);
        *(ushort4*)((char*)yl + addr) = o;
        if (d4 == 0)
            sumw[rr] = w0.x + w0.y + w0.z + w0.w + w1.x + w1.y + w1.z + w1.w;

        xr += (size_t)4 * NH * ND;
        #pragma unroll
        for (int h = 0; h < NH; ++h) cur[h] = nxt[h];
    }
    __syncthreads();

    // ---------------- phase 2: [16 x 512] @ W^T via bf16 MFMA ----------------
    // 8 waves, each owns 32 output cols (2 n-fragments of 16)
    const int lane = tid & 63;
    const int wv   = tid >> 6;           // 0..7
    const int n0   = wv * 32;
    const int lr   = lane & 15;          // A-row / B-col-within-frag
    const int lk   = (lane >> 4) * 8;    // k offset within 32

    f32x4 acc0 = {0.f, 0.f, 0.f, 0.f};
    f32x4 acc1 = {0.f, 0.f, 0.f, 0.f};

    const char* ylb = (const char*)yl + lr * 1024;
    const int swz = (lr & 7) << 4;

    #pragma unroll
    for (int ks = 0; ks < 16; ++ks) {
        const int k0 = ks * 32;
        const int kb = (k0 + lk) * 2;
        short8 a = *(const short8*)(ylb + (kb ^ swz));
        const ushort* wp = g_wb + (size_t)(n0 + lr) * ND + k0 + lk;
        short8 bf0 = *(const short8*)(wp);
        short8 bf1 = *(const short8*)(wp + 16 * ND);
        acc0 = __builtin_amdgcn_mfma_f32_16x16x32_bf16(a, bf0, acc0, 0, 0, 0);
        acc1 = __builtin_amdgcn_mfma_f32_16x16x32_bf16(a, bf1, acc1, 0, 0, 0);
    }

    // epilogue: D layout col = lane&15, row = (lane>>4)*4 + reg
    const int rbase = (lane >> 4) * 4;
    f32x4 accs[2] = {acc0, acc1};
    #pragma unroll
    for (int nf = 0; nf < 2; ++nf) {
        const int col = n0 + nf * 16 + lr;
        const float bn = bias[col];
        #pragma unroll
        for (int q = 0; q < 4; ++q) {
            const int r = rbase + q;
            out[(size_t)(b0 + r) * NO + col] = accs[nf][q] + bn * sumw[r];
        }
    }
}

extern "C" void kernel_launch(void* const* d_in, const int* in_sizes, int n_in,
                              void* d_out, int out_size, void* d_ws, size_t ws_size,
                              hipStream_t stream) {
    const float* x     = (const float*)d_in[0];
    const float* rw    = (const float*)d_in[1];
    const float* gamma = (const float*)d_in[2];
    const float* beta  = (const float*)d_in[3];
    const float* mean  = (const float*)d_in[4];
    const float* var   = (const float*)d_in[5];
    const float* W     = (const float*)d_in[6];
    const float* bias  = (const float*)d_in[7];
    float* out = (float*)d_out;

    hipLaunchKernelGGL(wcvt_kernel, dim3((NO * ND) / 1024), dim3(256), 0, stream, W);
    hipLaunchKernelGGL(fused_kernel, dim3(NB / ROWS), dim3(512), 0, stream,
                       x, rw, gamma, beta, mean, var, bias, out);
}